// Round 1
// baseline (254.200 us; speedup 1.0000x reference)
//
#include <hip/hip_runtime.h>
#include <cstdint>
#include <cstddef>

#define N_TOK 32768
#define DIM   1024
#define NE    64
#define BM    64
#define BK    32
#define NTILES (DIM / BK)   // 32

// global -> LDS direct DMA, 16B per lane; LDS dest = wave-uniform base + lane*16
__device__ __forceinline__ void gload16(const float* g, float* l) {
  __builtin_amdgcn_global_load_lds(
      (const __attribute__((address_space(1))) uint32_t*)g,
      (__attribute__((address_space(3))) uint32_t*)l, 16, 0, 0);
}

__global__ __launch_bounds__(256, 2) void router_kernel(
    const float* __restrict__ x, const float* __restrict__ W,
    const float* __restrict__ bias, float* __restrict__ probs,
    float* __restrict__ idxo) {
  // [buf][ x: 0..2047 (64 rows x 32 d, quad-swizzled), W: 2048..4095 (32 d x 64 e) ]
  __shared__ __align__(1024) float lds[2][4096];   // 32 KB total

  const int tid  = threadIdx.x;
  const int lane = tid & 63;
  const int wv   = __builtin_amdgcn_readfirstlane(tid >> 6);
  const int tx   = tid & 15;   // expert quad: experts tx*4..tx*4+3
  const int ty   = tid >> 4;   // row quad:    rows   ty*4..ty*4+3
  const int r0   = blockIdx.x * BM;

  // stage tile t into buffer b: W tile contiguous, x tile with per-row XOR quad swizzle
  auto stage = [&](int t, int b) {
    const int d0 = t * BK;
    float* xl = &lds[b][0];
    float* wl = &lds[b][2048];
#pragma unroll
    for (int q = 0; q < 2; ++q) {
      const int s = (wv * 2 + q) * 64 + lane;          // float4 slot 0..511
      // W[d0..d0+32)[0..64) : 8KB fully contiguous
      gload16(W + (size_t)d0 * NE + (size_t)s * 4, wl + (wv * 2 + q) * 256);
      // x: slot s -> (row = s/8, quad g = s%8); content = global quad (g ^ (row&7))
      const int row = s >> 3;
      const int g   = s & 7;
      gload16(x + (size_t)(r0 + row) * DIM + d0 + ((g ^ (row & 7)) << 2),
              xl + (wv * 2 + q) * 256);
    }
  };

  float4 acc[4];
#pragma unroll
  for (int i = 0; i < 4; ++i) acc[i] = make_float4(0.f, 0.f, 0.f, 0.f);

  stage(0, 0);

  for (int t = 0; t < NTILES; ++t) {
    const int b = t & 1;
    __syncthreads();                       // drains stage(t) (vmcnt) + protects buffers
    if (t + 1 < NTILES) stage(t + 1, (t + 1) & 1);   // prefetch overlaps compute

    const float* wl = &lds[b][2048];
    // per-row x base byte addresses with swizzle folded into low bits (base 128-aligned)
    uintptr_t xb[4];
#pragma unroll
    for (int i = 0; i < 4; ++i) {
      const int r = 4 * ty + i;
      xb[i] = (uintptr_t)(&lds[b][0]) + (uintptr_t)r * (BK * 4) + (uintptr_t)((r & 7) << 4);
    }

#pragma unroll
    for (int q = 0; q < 8; ++q) {
      float4 a0 = *(const float4*)(xb[0] ^ (uintptr_t)(q << 4));
      float4 a1 = *(const float4*)(xb[1] ^ (uintptr_t)(q << 4));
      float4 a2 = *(const float4*)(xb[2] ^ (uintptr_t)(q << 4));
      float4 a3 = *(const float4*)(xb[3] ^ (uintptr_t)(q << 4));
      float4 b0 = *(const float4*)(wl + (q * 4 + 0) * NE + tx * 4);
      float4 b1 = *(const float4*)(wl + (q * 4 + 1) * NE + tx * 4);
      float4 b2 = *(const float4*)(wl + (q * 4 + 2) * NE + tx * 4);
      float4 b3 = *(const float4*)(wl + (q * 4 + 3) * NE + tx * 4);

#define ROWFMA(ACC, A)                                                        \
      ACC.x = fmaf(A.x, b0.x, ACC.x); ACC.y = fmaf(A.x, b0.y, ACC.y);         \
      ACC.z = fmaf(A.x, b0.z, ACC.z); ACC.w = fmaf(A.x, b0.w, ACC.w);         \
      ACC.x = fmaf(A.y, b1.x, ACC.x); ACC.y = fmaf(A.y, b1.y, ACC.y);         \
      ACC.z = fmaf(A.y, b1.z, ACC.z); ACC.w = fmaf(A.y, b1.w, ACC.w);         \
      ACC.x = fmaf(A.z, b2.x, ACC.x); ACC.y = fmaf(A.z, b2.y, ACC.y);         \
      ACC.z = fmaf(A.z, b2.z, ACC.z); ACC.w = fmaf(A.z, b2.w, ACC.w);         \
      ACC.x = fmaf(A.w, b3.x, ACC.x); ACC.y = fmaf(A.w, b3.y, ACC.y);         \
      ACC.z = fmaf(A.w, b3.z, ACC.z); ACC.w = fmaf(A.w, b3.w, ACC.w);

      ROWFMA(acc[0], a0)
      ROWFMA(acc[1], a1)
      ROWFMA(acc[2], a2)
      ROWFMA(acc[3], a3)
#undef ROWFMA
    }
  }

  // ---------------- epilogue: bias + top-2 + 2-way softmax + scatter ----------------
  const float4 bv = *(const float4*)(bias + tx * 4);
#pragma unroll
  for (int i = 0; i < 4; ++i) {
    float4 l = acc[i];
    l.x += bv.x; l.y += bv.y; l.z += bv.z; l.w += bv.w;

    // local top-2 of 4 (tie -> lower index)
    float v1, v2; int j1, j2;
    if (l.y > l.x) { v1 = l.y; j1 = 1; v2 = l.x; j2 = 0; }
    else           { v1 = l.x; j1 = 0; v2 = l.y; j2 = 1; }
    if (l.z > v1)      { v2 = v1; j2 = j1; v1 = l.z; j1 = 2; }
    else if (l.z > v2) { v2 = l.z; j2 = 2; }
    if (l.w > v1)      { v2 = v1; j2 = j1; v1 = l.w; j1 = 3; }
    else if (l.w > v2) { v2 = l.w; j2 = 3; }
    j1 += tx * 4; j2 += tx * 4;

    // butterfly merge across the 16 lanes sharing this row (masks < 16 stay in-group)
#pragma unroll
    for (int m = 8; m >= 1; m >>= 1) {
      float u1 = __shfl_xor(v1, m, 64);
      int   k1 = __shfl_xor(j1, m, 64);
      float u2 = __shfl_xor(v2, m, 64);
      int   k2 = __shfl_xor(j2, m, 64);
      bool firstWins = (u1 > v1) || (u1 == v1 && k1 < j1);
      if (firstWins) {
        bool u2b = (u2 > v1) || (u2 == v1 && k2 < j1);
        v2 = u2b ? u2 : v1; j2 = u2b ? k2 : j1;
        v1 = u1; j1 = k1;
      } else if ((u1 > v2) || (u1 == v2 && k1 < j2)) {
        v2 = u1; j2 = k1;
      }
    }

    // softmax over {v1, v2} (v1 >= v2): p1 = 1/(1+e), p2 = e/(1+e)
    const float e2v = __expf(v2 - v1);
    const float inv = 1.0f / (1.0f + e2v);
    const float p1 = inv, p2 = e2v * inv;

    const int row = r0 + 4 * ty + i;
    const int e0  = tx * 4;
    float4 o;
    o.x = (e0 + 0 == j1) ? p1 : (e0 + 0 == j2) ? p2 : 0.0f;
    o.y = (e0 + 1 == j1) ? p1 : (e0 + 1 == j2) ? p2 : 0.0f;
    o.z = (e0 + 2 == j1) ? p1 : (e0 + 2 == j2) ? p2 : 0.0f;
    o.w = (e0 + 3 == j1) ? p1 : (e0 + 3 == j2) ? p2 : 0.0f;
    *(float4*)(probs + (size_t)row * NE + e0) = o;

    if (tx == 0) {
      float2 oi; oi.x = (float)j1; oi.y = (float)j2;
      *(float2*)(idxo + (size_t)row * 2) = oi;
    }
  }
}

extern "C" void kernel_launch(void* const* d_in, const int* in_sizes, int n_in,
                              void* d_out, int out_size, void* d_ws, size_t ws_size,
                              hipStream_t stream) {
  (void)in_sizes; (void)n_in; (void)out_size; (void)d_ws; (void)ws_size;
  const float* x = (const float*)d_in[0];
  const float* W = (const float*)d_in[1];
  const float* b = (const float*)d_in[2];
  float* out  = (float*)d_out;
  float* idxo = out + (size_t)N_TOK * NE;   // indices chunk follows probs chunk

  dim3 grid(N_TOK / BM);   // 512 blocks
  dim3 block(256);
  hipLaunchKernelGGL(router_kernel, grid, block, 0, stream, x, W, b, out, idxo);
}

// Round 2
// 248.611 us; speedup vs baseline: 1.0225x; 1.0225x over previous
//
#include <hip/hip_runtime.h>
#include <cstdint>
#include <cstddef>

#define N_TOK 32768
#define DIM   1024
#define NE    64
#define RPB   64          // rows per block (= lanes)
#define KHALF 512         // k range per wave
#define CHUNK 32          // k per staged chunk
#define NCHUNK (KHALF / CHUNK)   // 16

// global -> LDS direct DMA, 16B per lane; LDS dest = wave-uniform base + lane*16
__device__ __forceinline__ void gload16(const float* g, float* l) {
  __builtin_amdgcn_global_load_lds(
      (const __attribute__((address_space(1))) uint32_t*)g,
      (__attribute__((address_space(3))) uint32_t*)l, 16, 0, 0);
}

__global__ __launch_bounds__(512, 4) void router_kernel(
    const float* __restrict__ x, const float* __restrict__ W,
    const float* __restrict__ bias, float* __restrict__ probs,
    float* __restrict__ idxo) {
  // x staging: [half][buf][row 64][k 32], quad-swizzled within each row's 128B
  __shared__ __align__(1024) float xs[2][2][RPB][CHUNK];   // 32 KB
  __shared__ float  red[4][RPB][16];                       // 16 KB (k-reduction)
  __shared__ float4 ex[4][RPB];                            // 4 KB (per-group top2)
  __shared__ float4 ex2[RPB];                              // 1 KB (final result bcast)

  const int tid  = threadIdx.x;
  const int lane = tid & 63;
  const int w    = __builtin_amdgcn_readfirstlane(tid >> 6); // 0..7
  const int g    = w & 3;        // expert group: experts g*16 .. g*16+15
  const int h    = w >> 2;       // k half: k in [h*512, h*512+512)
  const int r0   = blockIdx.x * RPB;

  // stage chunk cc of half h into buffer cc&1. 8 KB; 8 DMA instrs split 2/wave
  // LDS slot s (0..7) of row r holds global quad (s ^ (r&7))  [bank swizzle]
  auto stage = [&](int cc) {
    const int buf = cc & 1;
    float* base = &xs[h][buf][0][0];
    const int k0 = h * KHALF + cc * CHUNK;
#pragma unroll
    for (int jj = 0; jj < 2; ++jj) {
      const int j = 2 * g + jj;                 // instr slot 0..7 (rows 8j..8j+7)
      const int row = 8 * j + (lane >> 3);      // row&7 == lane>>3
      const int sq  = (lane & 7) ^ (lane >> 3); // source global quad for this slot
      gload16(x + (size_t)(r0 + row) * DIM + k0 + (sq << 2),
              base + j * 256);
    }
  };

  float acc[16];
#pragma unroll
  for (int e = 0; e < 16; ++e) acc[e] = 0.0f;

  stage(0);

  for (int cc = 0; cc < NCHUNK; ++cc) {
    __syncthreads();                    // drains DMA for chunk cc, protects bufs
    if (cc + 1 < NCHUNK) stage(cc + 1);

    const int buf = cc & 1;
    const float* xb = &xs[h][buf][0][0] + lane * CHUNK;   // this lane's row
    const float* Wc = W + (size_t)(h * KHALF + cc * CHUNK) * NE + g * 16;

    float4 xq = make_float4(0.f, 0.f, 0.f, 0.f);
#pragma unroll
    for (int kk = 0; kk < CHUNK; ++kk) {
      if ((kk & 3) == 0) {
        const int slot = (kk >> 2) ^ (lane & 7);          // undo swizzle
        xq = *(const float4*)(xb + (slot << 2));
      }
      const float xc = ((kk & 3) == 0) ? xq.x
                     : ((kk & 3) == 1) ? xq.y
                     : ((kk & 3) == 2) ? xq.z : xq.w;
      const float* Wk = Wc + (size_t)kk * NE;   // 16 consecutive uniform floats
#pragma unroll
      for (int e = 0; e < 16; ++e)
        acc[e] = fmaf(Wk[e], xc, acc[e]);       // v_fmac: SGPR * VGPR + VGPR
    }
  }

  // ---- k-reduction: half-1 waves publish, half-0 waves accumulate ----
  __syncthreads();
  if (h == 1) {
#pragma unroll
    for (int q = 0; q < 4; ++q)
      *(float4*)&red[g][lane][q * 4] = make_float4(acc[q*4+0], acc[q*4+1],
                                                   acc[q*4+2], acc[q*4+3]);
  }
  __syncthreads();

  if (h == 0) {
#pragma unroll
    for (int q = 0; q < 4; ++q) {
      float4 r = *(const float4*)&red[g][lane][q * 4];
      acc[q*4+0] += r.x; acc[q*4+1] += r.y; acc[q*4+2] += r.z; acc[q*4+3] += r.w;
    }
    // bias (uniform scalar loads) then local top-2 of this 16-expert group
#pragma unroll
    for (int e = 0; e < 16; ++e) acc[e] += bias[g * 16 + e];

    float v1, v2; int j1, j2;
    if (acc[1] > acc[0]) { v1 = acc[1]; j1 = 1; v2 = acc[0]; j2 = 0; }
    else                 { v1 = acc[0]; j1 = 0; v2 = acc[1]; j2 = 1; }
#pragma unroll
    for (int e = 2; e < 16; ++e) {
      if (acc[e] > v1)      { v2 = v1; j2 = j1; v1 = acc[e]; j1 = e; }
      else if (acc[e] > v2) { v2 = acc[e]; j2 = e; }
    }
    ex[g][lane] = make_float4(v1, v2, (float)(g * 16 + j1), (float)(g * 16 + j2));
  }
  __syncthreads();

  if (w == 0) {   // merge the 4 groups (ascending g => strict '>' keeps lower idx)
    float4 m = ex[0][lane];
    float V1 = m.x, V2 = m.y, J1 = m.z, J2 = m.w;
#pragma unroll
    for (int gg = 1; gg < 4; ++gg) {
      float4 u = ex[gg][lane];
      if (u.x > V1) {
        bool s = (u.y > V1);
        V2 = s ? u.y : V1; J2 = s ? u.w : J1;
        V1 = u.x; J1 = u.z;
      } else if (u.x > V2) { V2 = u.x; J2 = u.z; }
    }
    const float e2 = __expf(V2 - V1);
    const float p1 = 1.0f / (1.0f + e2);
    const float p2 = e2 * p1;
    ex2[lane] = make_float4(J1, J2, p1, p2);
    float2 oi; oi.x = J1; oi.y = J2;
    *(float2*)(idxo + (size_t)(r0 + lane) * 2) = oi;
  }
  __syncthreads();

  if (h == 0) {   // scatter probs: each group-wave writes its 16-column slice
    float4 f = ex2[lane];
    const int ij1 = (int)f.x, ij2 = (int)f.y;
    float* op = probs + (size_t)(r0 + lane) * NE + g * 16;
#pragma unroll
    for (int q = 0; q < 4; ++q) {
      float4 o;
      const int e0 = g * 16 + q * 4;
      o.x = (e0 + 0 == ij1) ? f.z : (e0 + 0 == ij2) ? f.w : 0.0f;
      o.y = (e0 + 1 == ij1) ? f.z : (e0 + 1 == ij2) ? f.w : 0.0f;
      o.z = (e0 + 2 == ij1) ? f.z : (e0 + 2 == ij2) ? f.w : 0.0f;
      o.w = (e0 + 3 == ij1) ? f.z : (e0 + 3 == ij2) ? f.w : 0.0f;
      *(float4*)(op + q * 4) = o;
    }
  }
}

extern "C" void kernel_launch(void* const* d_in, const int* in_sizes, int n_in,
                              void* d_out, int out_size, void* d_ws, size_t ws_size,
                              hipStream_t stream) {
  (void)in_sizes; (void)n_in; (void)out_size; (void)d_ws; (void)ws_size;
  const float* x = (const float*)d_in[0];
  const float* W = (const float*)d_in[1];
  const float* b = (const float*)d_in[2];
  float* out  = (float*)d_out;
  float* idxo = out + (size_t)N_TOK * NE;   // indices chunk follows probs chunk

  dim3 grid(N_TOK / RPB);   // 512 blocks
  dim3 block(512);
  hipLaunchKernelGGL(router_kernel, grid, block, 0, stream, x, W, b, out, idxo);
}